// Round 1
// baseline (196.750 us; speedup 1.0000x reference)
//
#include <hip/hip_runtime.h>
#include <hip/hip_fp16.h>

#define NB   32
#define MF   16
#define KBITS 10
#define PP   8
#define DOUT 64
#define ROWS 1024
#define PXB  512

// round-to-nearest-even fp32 -> bf16 pair packed into u32 (lo in low 16 bits)
__device__ __forceinline__ unsigned bf16pair(float lo, float hi) {
    unsigned a = __float_as_uint(lo);
    unsigned b = __float_as_uint(hi);
    a = (a + 0x7fffu + ((a >> 16) & 1u)) >> 16;
    b = (b + 0x7fffu + ((b >> 16) & 1u)) & 0xffff0000u;
    return b | a;
}

__global__ __launch_bounds__(512, 2)
void fern_kernel(const float* __restrict__ B, const float* __restrict__ Wt,
                 const float* __restrict__ bias, float* __restrict__ out)
{
    // 144 KB LDS: [0 .. 32768) u32 = weights (1024 rows x 64 bf16)
    //             [32768 .. 36864) u32 = params (512 px x 8 p)
    // epilogue reuses the whole thing as float[64][515] transpose buffer
    __shared__ __align__(16) unsigned lds[36864];
    unsigned* ldsw = lds;
    unsigned* ldsp = lds + 32768;

    const int t   = threadIdx.x;
    const int wv  = t >> 6;
    const int ln  = t & 63;
    const int px8 = ln >> 3;
    const int cg  = ln & 7;

    const int gbase = blockIdx.x * PXB;
    const int n     = gbase >> 12;
    const int remb  = gbase & 4095;

    float acc[8][8];
#pragma unroll
    for (int r = 0; r < 8; ++r)
#pragma unroll
        for (int c = 0; c < 8; ++c) acc[r][c] = 0.f;

    for (int m = 0; m < MF; ++m) {
        // ---------- stage weights[m] -> LDS (fp32 -> bf16) ----------
        {
            const float4* src4 = (const float4*)(Wt + ((size_t)m << 16));
#pragma unroll
            for (int i = 0; i < 16; ++i) {
                const int q = i * 512 + t;          // 0..8191 (8-float chunks)
                const float4 f0 = src4[2 * q];
                const float4 f1 = src4[2 * q + 1];
                uint4 o;
                o.x = bf16pair(f0.x, f0.y);
                o.y = bf16pair(f0.z, f0.w);
                o.z = bf16pair(f1.x, f1.y);
                o.w = bf16pair(f1.z, f1.w);
                *(uint4*)&ldsw[q * 4] = o;
            }
        }
        // ---------- phase 1: per-pixel fern params ----------
        {
            const float* Bm = B + (((size_t)(n * (MF * KBITS) + m * KBITS)) << 12) + (remb + t);
            float T[KBITS], BA[KBITS];
            float bsp = 1.f;
            int wb = 0;
#pragma unroll
            for (int k = 0; k < KBITS; ++k) T[k] = Bm[(size_t)k << 12];
#pragma unroll
            for (int k = 0; k < KBITS; ++k) {
                wb |= (T[k] >= 0.5f) ? (1 << k) : 0;
                bsp *= fmaxf(T[k], 1.f - T[k]);
                BA[k] = fabsf(T[k] - 0.5f);
            }
            int abi0, abi1, abi2; float aba0, aba1, aba2;
            {
                int bi = 0; float bv = BA[0]; float tv = T[0];
#pragma unroll
                for (int k = 1; k < KBITS; ++k) if (BA[k] < bv) { bv = BA[k]; bi = k; tv = T[k]; }
                abi0 = bi; aba0 = tv;
#pragma unroll
                for (int k = 0; k < KBITS; ++k) BA[k] = (k == bi) ? (BA[k] + 1.f) : BA[k];
            }
            {
                int bi = 0; float bv = BA[0]; float tv = T[0];
#pragma unroll
                for (int k = 1; k < KBITS; ++k) if (BA[k] < bv) { bv = BA[k]; bi = k; tv = T[k]; }
                abi1 = bi; aba1 = tv;
#pragma unroll
                for (int k = 0; k < KBITS; ++k) BA[k] = (k == bi) ? (BA[k] + 1.f) : BA[k];
            }
            {
                int bi = 0; float bv = BA[0]; float tv = T[0];
#pragma unroll
                for (int k = 1; k < KBITS; ++k) if (BA[k] < bv) { bv = BA[k]; bi = k; tv = T[k]; }
                abi2 = bi; aba2 = tv;
            }
            float bspA = bsp / fmaxf(aba0, 1.f - aba0);
            bspA = bspA / fmaxf(aba1, 1.f - aba1);
            bspA = bspA / fmaxf(aba2, 1.f - aba2);
            const int mk0 = 1 << abi0, mk1 = 1 << abi1, mk2 = 1 << abi2;
#pragma unroll
            for (int p = 0; p < PP; ++p) {
                float at = (p & 1) ? aba0 : (1.f - aba0);
                at      *= (p & 2) ? aba1 : (1.f - aba1);
                at      *= (p & 4) ? aba2 : (1.f - aba2);
                at      *= bspA;
                int it = wb;
                it = (p & 1) ? (it | mk0) : (it & ~mk0);
                it = (p & 2) ? (it | mk1) : (it & ~mk1);
                it = (p & 4) ? (it | mk2) : (it & ~mk2);
                const unsigned u =
                    ((unsigned)__half_as_ushort(__float2half(at)) << 16) | (unsigned)it;
                ldsp[t * 8 + p] = u;
            }
        }
        __syncthreads();
        // ---------- phase 2: gather + accumulate ----------
        {
#pragma unroll
            for (int r = 0; r < 8; ++r) {
                const int pxl = wv * 64 + r * 8 + px8;
                const uint4 pa = *(const uint4*)&ldsp[pxl * 8];
                const uint4 pb = *(const uint4*)&ldsp[pxl * 8 + 4];
                const unsigned pu[8] = {pa.x, pa.y, pa.z, pa.w, pb.x, pb.y, pb.z, pb.w};
#pragma unroll
                for (int p = 0; p < PP; ++p) {
                    const unsigned u = pu[p];
                    const float at = __half2float(__ushort_as_half((unsigned short)(u >> 16)));
                    const int it = (int)(u & 1023u);
                    const uint4 w4 = *(const uint4*)&ldsw[it * 32 + cg * 4];
                    acc[r][0] = fmaf(at, __uint_as_float(w4.x << 16), acc[r][0]);
                    acc[r][1] = fmaf(at, __uint_as_float(w4.x & 0xffff0000u), acc[r][1]);
                    acc[r][2] = fmaf(at, __uint_as_float(w4.y << 16), acc[r][2]);
                    acc[r][3] = fmaf(at, __uint_as_float(w4.y & 0xffff0000u), acc[r][3]);
                    acc[r][4] = fmaf(at, __uint_as_float(w4.z << 16), acc[r][4]);
                    acc[r][5] = fmaf(at, __uint_as_float(w4.z & 0xffff0000u), acc[r][5]);
                    acc[r][6] = fmaf(at, __uint_as_float(w4.w << 16), acc[r][6]);
                    acc[r][7] = fmaf(at, __uint_as_float(w4.w & 0xffff0000u), acc[r][7]);
                }
            }
        }
        __syncthreads();
    }

    // ---------- epilogue: LDS transpose, add bias, coalesced store ----------
    float* ldst = (float*)lds;                    // [64][515]
#pragma unroll
    for (int r = 0; r < 8; ++r) {
        const int pxl = wv * 64 + r * 8 + px8;
#pragma unroll
        for (int c = 0; c < 8; ++c) {
            ldst[(cg * 8 + c) * 515 + pxl] = acc[r][c];
        }
    }
    __syncthreads();
    const size_t obase = ((size_t)n << 18) + (size_t)(remb + t);
    for (int d = 0; d < DOUT; ++d) {
        out[obase + ((size_t)d << 12)] = ldst[d * 515 + t] + bias[d];
    }
}

extern "C" void kernel_launch(void* const* d_in, const int* in_sizes, int n_in,
                              void* d_out, int out_size, void* d_ws, size_t ws_size,
                              hipStream_t stream) {
    (void)in_sizes; (void)n_in; (void)out_size; (void)d_ws; (void)ws_size;
    const float* B    = (const float*)d_in[0];
    const float* Wt   = (const float*)d_in[1];
    const float* bias = (const float*)d_in[2];
    float* out        = (float*)d_out;
    hipLaunchKernelGGL(fern_kernel, dim3(256), dim3(512), 0, stream, B, Wt, bias, out);
}

// Round 2
// 105.911 us; speedup vs baseline: 1.8577x; 1.8577x over previous
//
#include <hip/hip_runtime.h>
#include <hip/hip_fp16.h>

#define MF     16
#define PXB    512
#define WFERN  (1024 * 64)          // floats per fern table
#define WHALF_BYTES (WFERN * 2)     // 128 KB fp16 per fern

typedef const __attribute__((address_space(1))) unsigned gu32_t;
typedef __attribute__((address_space(3))) unsigned lu32_t;

__device__ __forceinline__ void gl_lds16(const void* g, void* l) {
    __builtin_amdgcn_global_load_lds((gu32_t*)g, (lu32_t*)l, 16, 0, 0);
}

__device__ __forceinline__ unsigned h2pack(float a, float b) {
    __half2 h = __floats2half2_rn(a, b);
    return __builtin_bit_cast(unsigned, h);
}

// fp32 -> fp16 weight prepack into workspace (runs every launch; deterministic)
__global__ void prepack_kernel(const float* __restrict__ Wt, unsigned* __restrict__ wsH) {
    const int q = blockIdx.x * 256 + threadIdx.x;       // 524288 total
    const float2 f = ((const float2*)Wt)[q];
    wsH[q] = h2pack(f.x, f.y);
}

template<bool USE_WS>
__global__ __launch_bounds__(1024)
void fern_kernel(const float* __restrict__ B, const float* __restrict__ Wt,
                 const unsigned* __restrict__ wsH,
                 const float* __restrict__ bias, float* __restrict__ out)
{
    // 144 KB LDS: [0 .. 32768) u32 = one fern's weights (1024 rows x 64 fp16)
    //             [32768 .. 36864) u32 = params: 2 planes of 512 x uint4
    // epilogue reuses everything as float[64][513]
    __shared__ __align__(16) unsigned lds[36864];
    unsigned* ldsw = lds;
    unsigned* ldsp = lds + 32768;

    const int t    = threadIdx.x;
    const int w    = t >> 6;        // wave 0..15
    const int ln   = t & 63;
    const int px8  = ln >> 3;       // 8 pixel slots per wave-step
    const int cg   = ln & 7;        // channel group (8 channels each)
    const int cgofs = cg * 16;      // byte offset within 128 B row

    const int gbase = blockIdx.x * PXB;
    const int n     = gbase >> 12;
    const int remb  = gbase & 4095;

    float acc[4][8];
#pragma unroll
    for (int r = 0; r < 4; ++r)
#pragma unroll
        for (int c = 0; c < 8; ++c) acc[r][c] = 0.f;

    const float* Bbase = B + (((size_t)n * (MF * 10)) << 12) + remb;

    // prologue: prefetch B bits for fern 0
    float T[10];
    if (t < 512) {
        const float* Bm = Bbase + t;
#pragma unroll
        for (int k = 0; k < 10; ++k) T[k] = Bm[(size_t)k << 12];
    }

    for (int m = 0; m < MF; ++m) {
        // ---------- stage weights[m] -> LDS ----------
        if (USE_WS) {
            const char* g = (const char*)wsH + (size_t)m * WHALF_BYTES + (w << 10) + (ln << 4);
            char* l = (char*)lds + (w << 10);
#pragma unroll
            for (int i = 0; i < 8; ++i)
                gl_lds16(g + i * 16384, l + i * 16384);
        } else {
            const float4* src4 = (const float4*)(Wt + ((size_t)m << 16));
#pragma unroll
            for (int i = 0; i < 8; ++i) {
                const int j = i * 1024 + t;         // uint4 chunk id, 0..8191
                const float4 f0 = src4[2 * j];
                const float4 f1 = src4[2 * j + 1];
                uint4 o;
                o.x = h2pack(f0.x, f0.y);
                o.y = h2pack(f0.z, f0.w);
                o.z = h2pack(f1.x, f1.y);
                o.w = h2pack(f1.z, f1.w);
                *(uint4*)&ldsw[j * 4] = o;
            }
        }

        // ---------- phase 1: per-pixel fern params (threads 0..511) ----------
        if (t < 512) {
            float BA[10]; float bsp = 1.f; int wb = 0;
#pragma unroll
            for (int k = 0; k < 10; ++k) {
                wb |= (T[k] >= 0.5f) ? (1 << k) : 0;
                bsp *= fmaxf(T[k], 1.f - T[k]);
                BA[k] = fabsf(T[k] - 0.5f);
            }
            int abi0, abi1, abi2; float aba0, aba1, aba2;
            {
                int bi = 0; float bv = BA[0]; float tv = T[0];
#pragma unroll
                for (int k = 1; k < 10; ++k) if (BA[k] < bv) { bv = BA[k]; bi = k; tv = T[k]; }
                abi0 = bi; aba0 = tv;
#pragma unroll
                for (int k = 0; k < 10; ++k) BA[k] = (k == bi) ? (BA[k] + 1.f) : BA[k];
            }
            {
                int bi = 0; float bv = BA[0]; float tv = T[0];
#pragma unroll
                for (int k = 1; k < 10; ++k) if (BA[k] < bv) { bv = BA[k]; bi = k; tv = T[k]; }
                abi1 = bi; aba1 = tv;
#pragma unroll
                for (int k = 0; k < 10; ++k) BA[k] = (k == bi) ? (BA[k] + 1.f) : BA[k];
            }
            {
                int bi = 0; float bv = BA[0]; float tv = T[0];
#pragma unroll
                for (int k = 1; k < 10; ++k) if (BA[k] < bv) { bv = BA[k]; bi = k; tv = T[k]; }
                abi2 = bi; aba2 = tv;
            }
            float bspA = bsp / fmaxf(aba0, 1.f - aba0);
            bspA /= fmaxf(aba1, 1.f - aba1);
            bspA /= fmaxf(aba2, 1.f - aba2);
            const int mk0 = 1 << abi0, mk1 = 1 << abi1, mk2 = 1 << abi2;
            unsigned uu[8];
#pragma unroll
            for (int p = 0; p < 8; ++p) {
                float at = ((p & 1) ? aba0 : (1.f - aba0));
                at      *= ((p & 2) ? aba1 : (1.f - aba1));
                at      *= ((p & 4) ? aba2 : (1.f - aba2));
                at      *= bspA;
                int it = wb;
                it = (p & 1) ? (it | mk0) : (it & ~mk0);
                it = (p & 2) ? (it | mk1) : (it & ~mk1);
                it = (p & 4) ? (it | mk2) : (it & ~mk2);
                unsigned ab = __float_as_uint(at);
                ab = (ab + 0x7fffu + ((ab >> 16) & 1u)) & 0xffff0000u;  // at as bf16 (hi16)
                uu[p] = ab | (unsigned)it;                              // low 10 bits = index
            }
            *(uint4*)&ldsp[t * 4]        = make_uint4(uu[0], uu[1], uu[2], uu[3]);
            *(uint4*)&ldsp[2048 + t * 4] = make_uint4(uu[4], uu[5], uu[6], uu[7]);
        }
        __syncthreads();   // staging complete (vmcnt drain) + params visible

        // prefetch next fern's B bits; latency hides under phase 2
        if (t < 512 && m + 1 < MF) {
            const float* Bm = Bbase + (((size_t)(m + 1) * 10) << 12) + t;
#pragma unroll
            for (int k = 0; k < 10; ++k) T[k] = Bm[(size_t)k << 12];
        }

        // ---------- phase 2: gather + accumulate ----------
#pragma unroll
        for (int r = 0; r < 4; ++r) {
            const int pxl = w * 32 + r * 8 + px8;
            const uint4 pa = *(const uint4*)&ldsp[pxl * 4];
            const uint4 pb = *(const uint4*)&ldsp[2048 + pxl * 4];
            const unsigned pus[8] = {pa.x, pa.y, pa.z, pa.w, pb.x, pb.y, pb.z, pb.w};
#pragma unroll
            for (int p = 0; p < 8; ++p) {
                const unsigned u = pus[p];
                const float atf = __uint_as_float(u);      // bf16 'at' + 2^-13 garbage: free
                const unsigned boff = ((u & 1023u) << 7) | (unsigned)cgofs;
                const uint4 w4 = *(const uint4*)((const char*)ldsw + boff);
                const __half2 h0 = __builtin_bit_cast(__half2, w4.x);
                const __half2 h1 = __builtin_bit_cast(__half2, w4.y);
                const __half2 h2 = __builtin_bit_cast(__half2, w4.z);
                const __half2 h3 = __builtin_bit_cast(__half2, w4.w);
                acc[r][0] = fmaf(atf, __low2float(h0),  acc[r][0]);
                acc[r][1] = fmaf(atf, __high2float(h0), acc[r][1]);
                acc[r][2] = fmaf(atf, __low2float(h1),  acc[r][2]);
                acc[r][3] = fmaf(atf, __high2float(h1), acc[r][3]);
                acc[r][4] = fmaf(atf, __low2float(h2),  acc[r][4]);
                acc[r][5] = fmaf(atf, __high2float(h2), acc[r][5]);
                acc[r][6] = fmaf(atf, __low2float(h3),  acc[r][6]);
                acc[r][7] = fmaf(atf, __high2float(h3), acc[r][7]);
            }
        }
        __syncthreads();   // phase-2 reads done before next stage/params overwrite
    }

    // ---------- epilogue: LDS transpose (stride 513), bias, coalesced store ----------
    float* ldst = (float*)lds;
#pragma unroll
    for (int r = 0; r < 4; ++r) {
        const int pxl = w * 32 + r * 8 + px8;
#pragma unroll
        for (int c = 0; c < 8; ++c)
            ldst[(cg * 8 + c) * 513 + pxl] = acc[r][c];
    }
    __syncthreads();
    const int tt = t & 511, hh = t >> 9;
    const size_t obase = ((size_t)n << 18) + (size_t)(remb + tt);
#pragma unroll
    for (int d = 0; d < 32; ++d) {
        const int ch = hh * 32 + d;
        out[obase + ((size_t)ch << 12)] = ldst[ch * 513 + tt] + bias[ch];
    }
}

extern "C" void kernel_launch(void* const* d_in, const int* in_sizes, int n_in,
                              void* d_out, int out_size, void* d_ws, size_t ws_size,
                              hipStream_t stream) {
    (void)in_sizes; (void)n_in; (void)out_size;
    const float* B    = (const float*)d_in[0];
    const float* Wt   = (const float*)d_in[1];
    const float* bias = (const float*)d_in[2];
    float* out        = (float*)d_out;

    const size_t need = (size_t)MF * WHALF_BYTES;   // 2 MB fp16 weights
    if (ws_size >= need) {
        unsigned* wsH = (unsigned*)d_ws;
        hipLaunchKernelGGL(prepack_kernel, dim3(2048), dim3(256), 0, stream, Wt, wsH);
        hipLaunchKernelGGL((fern_kernel<true>), dim3(256), dim3(1024), 0, stream,
                           B, Wt, wsH, bias, out);
    } else {
        hipLaunchKernelGGL((fern_kernel<false>), dim3(256), dim3(1024), 0, stream,
                           B, Wt, (const unsigned*)nullptr, bias, out);
    }
}

// Round 3
// 93.062 us; speedup vs baseline: 2.1142x; 1.1381x over previous
//
#include <hip/hip_runtime.h>
#include <hip/hip_fp16.h>

#define MF     16
#define PXB    512
#define WHALF_BYTES (1024 * 64 * 2)     // 128 KB fp16 per fern

typedef const __attribute__((address_space(1))) unsigned gu32_t;
typedef __attribute__((address_space(3))) unsigned lu32_t;

__device__ __forceinline__ void gl_lds16(const void* g, void* l) {
    __builtin_amdgcn_global_load_lds((gu32_t*)g, (lu32_t*)l, 16, 0, 0);
}

__device__ __forceinline__ unsigned h2pack(float a, float b) {
    __half2 h = __floats2half2_rn(a, b);
    return __builtin_bit_cast(unsigned, h);
}

// acc += atf * f16(lo/hi of w32)   — forced v_fma_mix_f32, no cvt/unpack VALU
#define FMAMIX_LO(ACC, A, W) \
    asm("v_fma_mix_f32 %0, %1, %2, %0 op_sel:[0,0,0] op_sel_hi:[0,1,0]" \
        : "+v"(ACC) : "v"(A), "v"(W))
#define FMAMIX_HI(ACC, A, W) \
    asm("v_fma_mix_f32 %0, %1, %2, %0 op_sel:[0,1,0] op_sel_hi:[0,1,0]" \
        : "+v"(ACC) : "v"(A), "v"(W))

// fp32 -> fp16 prepack, XOR-row-swizzled: chunk c (16B) of row r stored at
// slot c^(r&7). LDS stays linear (global_load_lds), source is pre-permuted.
__global__ void prepack_kernel(const float* __restrict__ Wt, unsigned* __restrict__ wsH) {
    const int q   = blockIdx.x * 256 + threadIdx.x;   // u32 id, 0..524287
    const int m   = q >> 15;
    const int q32 = q & 32767;
    const int row = q32 >> 5;
    const int slt = (q32 >> 2) & 7;
    const int j   = q32 & 3;
    const int c   = slt ^ (row & 7);
    const float2 f = ((const float2*)Wt)[((m << 10) + row) * 32 + c * 4 + j];
    wsH[q] = h2pack(f.x, f.y);
}

template<bool USE_WS>
__global__ __launch_bounds__(1024, 4)
void fern_kernel(const float* __restrict__ B, const float* __restrict__ Wt,
                 const unsigned* __restrict__ wsH,
                 const float* __restrict__ bias, float* __restrict__ out)
{
    // LDS (u32 units): [0,32768) weights fp16 swizzled; [32768,36864) at-plane
    // (512px x 8 fp32); [36864,38912) idx-plane (512px x 8 u16, pre-shifted <<4).
    // Epilogue reuses as float[64][513]. Total 152 KB.
    __shared__ __align__(16) unsigned lds[38912];
    unsigned* ldsw = lds;
    float*    ldsa = (float*)(lds + 32768);
    unsigned* ldsi = lds + 36864;

    const int t   = threadIdx.x;
    const int w   = t >> 6;
    const int ln  = t & 63;
    const int px8 = ln >> 3;
    const int cg  = ln & 7;
    const unsigned cg4 = (unsigned)cg << 4;

    const int gbase = blockIdx.x * PXB;
    const int n     = gbase >> 12;
    const int remb  = gbase & 4095;

    float acc[4][8];
#pragma unroll
    for (int r = 0; r < 4; ++r)
#pragma unroll
        for (int c = 0; c < 8; ++c) acc[r][c] = 0.f;

    const float* Bbase = B + (((size_t)n * (MF * 10)) << 12) + remb;

    float T[10];
    if (t < 512) {
        const float* Bm = Bbase + t;
#pragma unroll
        for (int k = 0; k < 10; ++k) T[k] = Bm[(size_t)k << 12];
    }

    for (int m = 0; m < MF; ++m) {
        // ---------- stage weights[m] -> LDS ----------
        if (USE_WS) {
            const char* g = (const char*)wsH + (size_t)m * WHALF_BYTES + (w << 10) + (ln << 4);
            char* l = (char*)lds + (w << 10);
#pragma unroll
            for (int i = 0; i < 8; ++i)
                gl_lds16(g + i * 16384, l + i * 16384);
        } else {
            const float4* src4 = (const float4*)(Wt + ((size_t)m << 16));
#pragma unroll
            for (int i = 0; i < 8; ++i) {
                const int j16 = i * 1024 + t;             // 16B slot id
                const int row = j16 >> 3, slt = j16 & 7;
                const int c   = slt ^ (row & 7);
                const float4 f0 = src4[row * 16 + c * 2];
                const float4 f1 = src4[row * 16 + c * 2 + 1];
                uint4 o;
                o.x = h2pack(f0.x, f0.y);
                o.y = h2pack(f0.z, f0.w);
                o.z = h2pack(f1.x, f1.y);
                o.w = h2pack(f1.z, f1.w);
                *(uint4*)&ldsw[j16 * 4] = o;
            }
        }

        // ---------- phase 1: per-pixel fern params ----------
        if (t < 512) {
            float BA[10]; float bsp = 1.f; int wb = 0;
#pragma unroll
            for (int k = 0; k < 10; ++k) {
                wb |= (T[k] >= 0.5f) ? (1 << k) : 0;
                bsp *= fmaxf(T[k], 1.f - T[k]);
                BA[k] = fabsf(T[k] - 0.5f);
            }
            int abi0, abi1, abi2; float aba0, aba1, aba2;
            {
                int bi = 0; float bv = BA[0]; float tv = T[0];
#pragma unroll
                for (int k = 1; k < 10; ++k) if (BA[k] < bv) { bv = BA[k]; bi = k; tv = T[k]; }
                abi0 = bi; aba0 = tv;
#pragma unroll
                for (int k = 0; k < 10; ++k) BA[k] = (k == bi) ? (BA[k] + 1.f) : BA[k];
            }
            {
                int bi = 0; float bv = BA[0]; float tv = T[0];
#pragma unroll
                for (int k = 1; k < 10; ++k) if (BA[k] < bv) { bv = BA[k]; bi = k; tv = T[k]; }
                abi1 = bi; aba1 = tv;
#pragma unroll
                for (int k = 0; k < 10; ++k) BA[k] = (k == bi) ? (BA[k] + 1.f) : BA[k];
            }
            {
                int bi = 0; float bv = BA[0]; float tv = T[0];
#pragma unroll
                for (int k = 1; k < 10; ++k) if (BA[k] < bv) { bv = BA[k]; bi = k; tv = T[k]; }
                abi2 = bi; aba2 = tv;
            }
            float bspA = bsp / fmaxf(aba0, 1.f - aba0);
            bspA /= fmaxf(aba1, 1.f - aba1);
            bspA /= fmaxf(aba2, 1.f - aba2);
            const int mk0 = 1 << abi0, mk1 = 1 << abi1, mk2 = 1 << abi2;
            float atv[8]; unsigned iv[8];
#pragma unroll
            for (int p = 0; p < 8; ++p) {
                float at = ((p & 1) ? aba0 : (1.f - aba0));
                at      *= ((p & 2) ? aba1 : (1.f - aba1));
                at      *= ((p & 4) ? aba2 : (1.f - aba2));
                atv[p]   = at * bspA;
                int it = wb;
                it = (p & 1) ? (it | mk0) : (it & ~mk0);
                it = (p & 2) ? (it | mk1) : (it & ~mk1);
                it = (p & 4) ? (it | mk2) : (it & ~mk2);
                iv[p] = (unsigned)it << 4;               // pre-shifted
            }
            *(float4*)&ldsa[t * 8]     = make_float4(atv[0], atv[1], atv[2], atv[3]);
            *(float4*)&ldsa[t * 8 + 4] = make_float4(atv[4], atv[5], atv[6], atv[7]);
            *(uint4*)&ldsi[t * 4] = make_uint4((iv[1] << 16) | iv[0], (iv[3] << 16) | iv[2],
                                               (iv[5] << 16) | iv[4], (iv[7] << 16) | iv[6]);
        }
        __syncthreads();   // staging drained + params visible

        // prefetch next fern's B bits; latency hides under phase 2
        if (t < 512 && m + 1 < MF) {
            const float* Bm = Bbase + (((size_t)(m + 1) * 10) << 12) + t;
#pragma unroll
            for (int k = 0; k < 10; ++k) T[k] = Bm[(size_t)k << 12];
        }

        // ---------- phase 2: gather + accumulate ----------
#pragma unroll
        for (int r = 0; r < 4; ++r) {
            const int pxl = w * 32 + r * 8 + px8;
            const float4 a0 = *(const float4*)&ldsa[pxl * 8];
            const float4 a1 = *(const float4*)&ldsa[pxl * 8 + 4];
            const uint4  ix = *(const uint4*)&ldsi[pxl * 4];
            unsigned vv[8];
            vv[0] = ix.x & 0xFFFFu; vv[1] = ix.x >> 16;
            vv[2] = ix.y & 0xFFFFu; vv[3] = ix.y >> 16;
            vv[4] = ix.z & 0xFFFFu; vv[5] = ix.z >> 16;
            vv[6] = ix.w & 0xFFFFu; vv[7] = ix.w >> 16;
            uint4 w4s[8];
#pragma unroll
            for (int p = 0; p < 8; ++p) {
                const unsigned boff = (vv[p] << 3) | ((vv[p] ^ cg4) & 0x70u);
                w4s[p] = *(const uint4*)((const char*)ldsw + boff);
            }
            const float atf[8] = {a0.x, a0.y, a0.z, a0.w, a1.x, a1.y, a1.z, a1.w};
#pragma unroll
            for (int p = 0; p < 8; ++p) {
                FMAMIX_LO(acc[r][0], atf[p], w4s[p].x);
                FMAMIX_HI(acc[r][1], atf[p], w4s[p].x);
                FMAMIX_LO(acc[r][2], atf[p], w4s[p].y);
                FMAMIX_HI(acc[r][3], atf[p], w4s[p].y);
                FMAMIX_LO(acc[r][4], atf[p], w4s[p].z);
                FMAMIX_HI(acc[r][5], atf[p], w4s[p].z);
                FMAMIX_LO(acc[r][6], atf[p], w4s[p].w);
                FMAMIX_HI(acc[r][7], atf[p], w4s[p].w);
            }
        }
        __syncthreads();
    }

    // ---------- epilogue: LDS transpose (stride 513), bias, coalesced store ----------
    float* ldst = (float*)lds;
#pragma unroll
    for (int r = 0; r < 4; ++r) {
        const int pxl = w * 32 + r * 8 + px8;
#pragma unroll
        for (int c = 0; c < 8; ++c)
            ldst[(cg * 8 + c) * 513 + pxl] = acc[r][c];
    }
    __syncthreads();
    const int tt = t & 511, hh = t >> 9;
    const size_t obase = ((size_t)n << 18) + (size_t)(remb + tt);
#pragma unroll
    for (int d = 0; d < 32; ++d) {
        const int ch = hh * 32 + d;
        out[obase + ((size_t)ch << 12)] = ldst[ch * 513 + tt] + bias[ch];
    }
}

extern "C" void kernel_launch(void* const* d_in, const int* in_sizes, int n_in,
                              void* d_out, int out_size, void* d_ws, size_t ws_size,
                              hipStream_t stream) {
    (void)in_sizes; (void)n_in; (void)out_size;
    const float* B    = (const float*)d_in[0];
    const float* Wt   = (const float*)d_in[1];
    const float* bias = (const float*)d_in[2];
    float* out        = (float*)d_out;

    const size_t need = (size_t)MF * WHALF_BYTES;   // 2 MB fp16 weights
    if (ws_size >= need) {
        unsigned* wsH = (unsigned*)d_ws;
        hipLaunchKernelGGL(prepack_kernel, dim3(2048), dim3(256), 0, stream, Wt, wsH);
        hipLaunchKernelGGL((fern_kernel<true>), dim3(256), dim3(1024), 0, stream,
                           B, Wt, wsH, bias, out);
    } else {
        hipLaunchKernelGGL((fern_kernel<false>), dim3(256), dim3(1024), 0, stream,
                           B, Wt, (const unsigned*)nullptr, bias, out);
    }
}

// Round 4
// 82.274 us; speedup vs baseline: 2.3914x; 1.1311x over previous
//
#include <hip/hip_runtime.h>
#include <hip/hip_fp16.h>

#define MF     16
#define PXB    512
#define WHALF_BYTES (1024 * 64 * 2)     // 128 KB fp16 per fern

typedef const __attribute__((address_space(1))) unsigned gu32_t;
typedef __attribute__((address_space(3))) unsigned lu32_t;

__device__ __forceinline__ void gl_lds16(const void* g, void* l) {
    __builtin_amdgcn_global_load_lds((gu32_t*)g, (lu32_t*)l, 16, 0, 0);
}

__device__ __forceinline__ unsigned h2pack(float a, float b) {
    __half2 h = __floats2half2_rn(a, b);
    return __builtin_bit_cast(unsigned, h);
}

// D(f16x2) = W(f16x2) * broadcast(hi16(U) as f16) + D   — one instr, 2 MACs
#define PKFMA(D, W, U) \
    asm("v_pk_fma_f16 %0, %1, %2, %0 op_sel:[0,1,0] op_sel_hi:[1,1,1]" \
        : "+v"(D) : "v"(W), "v"(U))
// D(f16x2) = W(f16x2) * broadcast(hi16(U) as f16)
#define PKMUL(D, W, U) \
    asm("v_pk_mul_f16 %0, %1, %2 op_sel:[0,1] op_sel_hi:[1,1]" \
        : "=v"(D) : "v"(W), "v"(U))
// ACC(f32) += f16(lo/hi of P) * 1.0   — up-convert + accumulate in one instr
#define MIXADD_LO(ACC, P) \
    asm("v_fma_mix_f32 %0, %1, 1.0, %0 op_sel:[0,0,0] op_sel_hi:[1,0,0]" \
        : "+v"(ACC) : "v"(P))
#define MIXADD_HI(ACC, P) \
    asm("v_fma_mix_f32 %0, %1, 1.0, %0 op_sel:[1,0,0] op_sel_hi:[1,0,0]" \
        : "+v"(ACC) : "v"(P))

// fp32 -> fp16 weight prepack (linear layout; swizzle reverted)
__global__ void prepack_kernel(const float* __restrict__ Wt, unsigned* __restrict__ wsH) {
    const int q = blockIdx.x * 256 + threadIdx.x;       // 524288 total
    const float2 f = ((const float2*)Wt)[q];
    wsH[q] = h2pack(f.x, f.y);
}

template<bool USE_WS>
__global__ __launch_bounds__(1024, 4)
void fern_kernel(const float* __restrict__ B, const float* __restrict__ Wt,
                 const unsigned* __restrict__ wsH,
                 const float* __restrict__ bias, float* __restrict__ out)
{
    // LDS (u32): [0,32768) weights fp16 linear; [32768,34816) param plane0
    // (p0..3); [34816,36864) param plane1 (p4..7). 144 KB total.
    // Epilogue reuses everything as float[64][513].
    __shared__ __align__(16) unsigned lds[36864];
    unsigned* ldsw = lds;
    unsigned* ldsp0 = lds + 32768;
    unsigned* ldsp1 = lds + 34816;

    const int t   = threadIdx.x;
    const int w   = t >> 6;
    const int ln  = t & 63;
    const int px8 = ln >> 3;
    const int cg  = ln & 7;
    const unsigned cg4 = (unsigned)cg << 4;   // byte offset within 128 B row

    const int gbase = blockIdx.x * PXB;
    const int n     = gbase >> 12;
    const int remb  = gbase & 4095;

    float acc[4][8];
#pragma unroll
    for (int r = 0; r < 4; ++r)
#pragma unroll
        for (int c = 0; c < 8; ++c) acc[r][c] = 0.f;

    const float* Bbase = B + (((size_t)n * (MF * 10)) << 12) + remb;

    float T[10];
    if (t < 512) {
        const float* Bm = Bbase + t;
#pragma unroll
        for (int k = 0; k < 10; ++k) T[k] = Bm[(size_t)k << 12];
    }

    for (int m = 0; m < MF; ++m) {
        // ---------- stage weights[m] -> LDS (linear) ----------
        if (USE_WS) {
            const char* g = (const char*)wsH + (size_t)m * WHALF_BYTES + (w << 10) + (ln << 4);
            char* l = (char*)lds + (w << 10);
#pragma unroll
            for (int i = 0; i < 8; ++i)
                gl_lds16(g + i * 16384, l + i * 16384);
        } else {
            const float4* src4 = (const float4*)(Wt + ((size_t)m << 16));
#pragma unroll
            for (int i = 0; i < 8; ++i) {
                const int j = i * 1024 + t;
                const float4 f0 = src4[2 * j];
                const float4 f1 = src4[2 * j + 1];
                uint4 o;
                o.x = h2pack(f0.x, f0.y);
                o.y = h2pack(f0.z, f0.w);
                o.z = h2pack(f1.x, f1.y);
                o.w = h2pack(f1.z, f1.w);
                *(uint4*)&ldsw[j * 4] = o;
            }
        }

        // ---------- phase 1: per-pixel fern params ----------
        if (t < 512) {
            float BA[10]; float bsp = 1.f; int wb = 0;
#pragma unroll
            for (int k = 0; k < 10; ++k) {
                wb |= (T[k] >= 0.5f) ? (1 << k) : 0;
                bsp *= fmaxf(T[k], 1.f - T[k]);
                BA[k] = fabsf(T[k] - 0.5f);
            }
            int abi0, abi1, abi2; float aba0, aba1, aba2;
            {
                int bi = 0; float bv = BA[0]; float tv = T[0];
#pragma unroll
                for (int k = 1; k < 10; ++k) if (BA[k] < bv) { bv = BA[k]; bi = k; tv = T[k]; }
                abi0 = bi; aba0 = tv;
#pragma unroll
                for (int k = 0; k < 10; ++k) BA[k] = (k == bi) ? (BA[k] + 1.f) : BA[k];
            }
            {
                int bi = 0; float bv = BA[0]; float tv = T[0];
#pragma unroll
                for (int k = 1; k < 10; ++k) if (BA[k] < bv) { bv = BA[k]; bi = k; tv = T[k]; }
                abi1 = bi; aba1 = tv;
#pragma unroll
                for (int k = 0; k < 10; ++k) BA[k] = (k == bi) ? (BA[k] + 1.f) : BA[k];
            }
            {
                int bi = 0; float bv = BA[0]; float tv = T[0];
#pragma unroll
                for (int k = 1; k < 10; ++k) if (BA[k] < bv) { bv = BA[k]; bi = k; tv = T[k]; }
                abi2 = bi; aba2 = tv;
            }
            const float m0 = fmaxf(aba0, 1.f - aba0);
            const float m1 = fmaxf(aba1, 1.f - aba1);
            const float m2 = fmaxf(aba2, 1.f - aba2);
            const float bspA = bsp * __builtin_amdgcn_rcpf(m0 * m1 * m2);
            const int mk0 = 1 << abi0, mk1 = 1 << abi1, mk2 = 1 << abi2;
            unsigned uu[8];
#pragma unroll
            for (int p = 0; p < 8; ++p) {
                float at = ((p & 1) ? aba0 : (1.f - aba0));
                at      *= ((p & 2) ? aba1 : (1.f - aba1));
                at      *= ((p & 4) ? aba2 : (1.f - aba2));
                at      *= bspA;
                int it = wb;
                it = (p & 1) ? (it | mk0) : (it & ~mk0);
                it = (p & 2) ? (it | mk1) : (it & ~mk1);
                it = (p & 4) ? (it | mk2) : (it & ~mk2);
                uu[p] = ((unsigned)__half_as_ushort(__float2half_rn(at)) << 16)
                      | ((unsigned)it << 4);
            }
            *(uint4*)&ldsp0[t * 4] = make_uint4(uu[0], uu[1], uu[2], uu[3]);
            *(uint4*)&ldsp1[t * 4] = make_uint4(uu[4], uu[5], uu[6], uu[7]);
        }
        __syncthreads();   // staging drained + params visible

        // prefetch next fern's B bits; latency hides under phase 2
        if (t < 512 && m + 1 < MF) {
            const float* Bm = Bbase + (((size_t)(m + 1) * 10) << 12) + t;
#pragma unroll
            for (int k = 0; k < 10; ++k) T[k] = Bm[(size_t)k << 12];
        }

        // ---------- phase 2: gather + packed-fp16 accumulate ----------
#pragma unroll
        for (int r = 0; r < 4; ++r) {
            const int pxl = w * 32 + r * 8 + px8;
            const uint4 pa = *(const uint4*)&ldsp0[pxl * 4];
            const uint4 pb = *(const uint4*)&ldsp1[pxl * 4];
            const unsigned pu[8] = {pa.x, pa.y, pa.z, pa.w, pb.x, pb.y, pb.z, pb.w};
            unsigned a01, a23, a45, a67;     // fp16-pair per-fern partials
            {
                const unsigned u = pu[0];
                const unsigned boff = ((u & 0x3FF0u) << 3) + cg4;
                const uint4 w4 = *(const uint4*)((const char*)ldsw + boff);
                PKMUL(a01, w4.x, u);
                PKMUL(a23, w4.y, u);
                PKMUL(a45, w4.z, u);
                PKMUL(a67, w4.w, u);
            }
#pragma unroll
            for (int p = 1; p < 8; ++p) {
                const unsigned u = pu[p];
                const unsigned boff = ((u & 0x3FF0u) << 3) + cg4;
                const uint4 w4 = *(const uint4*)((const char*)ldsw + boff);
                PKFMA(a01, w4.x, u);
                PKFMA(a23, w4.y, u);
                PKFMA(a45, w4.z, u);
                PKFMA(a67, w4.w, u);
            }
            MIXADD_LO(acc[r][0], a01); MIXADD_HI(acc[r][1], a01);
            MIXADD_LO(acc[r][2], a23); MIXADD_HI(acc[r][3], a23);
            MIXADD_LO(acc[r][4], a45); MIXADD_HI(acc[r][5], a45);
            MIXADD_LO(acc[r][6], a67); MIXADD_HI(acc[r][7], a67);
        }
        __syncthreads();
    }

    // ---------- epilogue: LDS transpose (stride 513), bias, coalesced store ----------
    float* ldst = (float*)lds;
#pragma unroll
    for (int r = 0; r < 4; ++r) {
        const int pxl = w * 32 + r * 8 + px8;
#pragma unroll
        for (int c = 0; c < 8; ++c)
            ldst[(cg * 8 + c) * 513 + pxl] = acc[r][c];
    }
    __syncthreads();
    const int tt = t & 511, hh = t >> 9;
    const size_t obase = ((size_t)n << 18) + (size_t)(remb + tt);
#pragma unroll
    for (int d = 0; d < 32; ++d) {
        const int ch = hh * 32 + d;
        out[obase + ((size_t)ch << 12)] = ldst[ch * 513 + tt] + bias[ch];
    }
}

extern "C" void kernel_launch(void* const* d_in, const int* in_sizes, int n_in,
                              void* d_out, int out_size, void* d_ws, size_t ws_size,
                              hipStream_t stream) {
    (void)in_sizes; (void)n_in; (void)out_size;
    const float* B    = (const float*)d_in[0];
    const float* Wt   = (const float*)d_in[1];
    const float* bias = (const float*)d_in[2];
    float* out        = (float*)d_out;

    const size_t need = (size_t)MF * WHALF_BYTES;   // 2 MB fp16 weights
    if (ws_size >= need) {
        unsigned* wsH = (unsigned*)d_ws;
        hipLaunchKernelGGL(prepack_kernel, dim3(2048), dim3(256), 0, stream, Wt, wsH);
        hipLaunchKernelGGL((fern_kernel<true>), dim3(256), dim3(1024), 0, stream,
                           B, Wt, wsH, bias, out);
    } else {
        hipLaunchKernelGGL((fern_kernel<false>), dim3(256), dim3(1024), 0, stream,
                           B, Wt, (const unsigned*)nullptr, bias, out);
    }
}